// Round 1
// baseline (329.698 us; speedup 1.0000x reference)
//
#include <hip/hip_runtime.h>

#define NN 2048

// One thread owns one row. Exact sequential Givens chain:
//   apply G_{n-1}, ..., G_0 to v = x[row,:], where G_k mixes (k, k+1 mod n):
//   v[k]   <- c_k*v[k] - s_k*v[k+1]
//   v[k+1] <- s_k*v[k] + c_k*v[k+1]
// Only a single carry value `a` is live; finals are emitted as we go.
__global__ __launch_bounds__(64) void ring_givens_kernel(
        const float* __restrict__ x,
        const float* __restrict__ angles,
        float* __restrict__ y) {
    __shared__ float2 cs[NN];  // (c, s) pairs, 16 KB; broadcast reads (conflict-free)
    for (int k = (int)threadIdx.x; k < NN; k += 64) {
        float s, c;
        sincosf(angles[k], &s, &c);
        cs[k] = make_float2(c, s);
    }
    __syncthreads();

    const int row = blockIdx.x * 64 + threadIdx.x;
    const float* __restrict__ xr = x + (size_t)row * NN;
    float* __restrict__ yr = y + (size_t)row * NN;

    const float x0 = xr[0];
    const float xl = xr[NN - 1];
    const float2 ce = cs[NN - 1];
    float a        = ce.x * xl - ce.y * x0;  // a_{n-1} (v[n-1] after step n-1)
    const float t0 = ce.y * xl + ce.x * x0;  // v[0] after step n-1

    // head scalar steps k = 2046, 2045, 2044 (align chunk loads to 16B)
    #pragma unroll
    for (int k = NN - 2; k >= NN - 4; --k) {
        float xk = xr[k];
        float2 q = cs[k];
        yr[k + 1] = q.y * xk + q.x * a;
        a = q.x * xk - q.y * a;
    }

    // main chunks: k = 2043 down to 7, float4 load covers x[k-3..k] (16B-aligned)
    #pragma unroll 4
    for (int k = NN - 5; k >= 7; k -= 4) {
        float4 xv = *(const float4*)(xr + (k - 3));
        float2 q3 = cs[k];
        float2 q2 = cs[k - 1];
        float2 q1 = cs[k - 2];
        float2 q0 = cs[k - 3];
        yr[k + 1] = q3.y * xv.w + q3.x * a;  a = q3.x * xv.w - q3.y * a;
        yr[k    ] = q2.y * xv.z + q2.x * a;  a = q2.x * xv.z - q2.y * a;
        yr[k - 1] = q1.y * xv.y + q1.x * a;  a = q1.x * xv.y - q1.y * a;
        yr[k - 2] = q0.y * xv.x + q0.x * a;  a = q0.x * xv.x - q0.y * a;
    }

    // tail scalar steps k = 3, 2, 1
    #pragma unroll
    for (int k = 3; k >= 1; --k) {
        float xk = xr[k];
        float2 q = cs[k];
        yr[k + 1] = q.y * xk + q.x * a;
        a = q.x * xk - q.y * a;
    }

    // step 0 mixes (0, 1) using t0 (v[0] updated by step n-1) and a = a_1
    float2 q0 = cs[0];
    yr[1] = q0.y * t0 + q0.x * a;
    yr[0] = q0.x * t0 - q0.y * a;
}

extern "C" void kernel_launch(void* const* d_in, const int* in_sizes, int n_in,
                              void* d_out, int out_size, void* d_ws, size_t ws_size,
                              hipStream_t stream) {
    const float* x      = (const float*)d_in[0];
    const float* angles = (const float*)d_in[1];
    float* y            = (float*)d_out;

    const int B = in_sizes[0] / NN;          // 16384
    const int grid = B / 64;                 // 256 blocks x 64 threads = 1 row/thread
    hipLaunchKernelGGL(ring_givens_kernel, dim3(grid), dim3(64), 0, stream,
                       x, angles, y);
}